// Round 3
// baseline (496.594 us; speedup 1.0000x reference)
//
#include <hip/hip_runtime.h>
#include <math.h>

#define NT 512      // 8 waves, single block, single CU
#define EPT 8       // NT*EPT = 4096
#define NN 4096
#define MM 9
#define NIT 50

// geometric carry weights (per-thread hop decay 2^-8)
#define W256_1 3.90625e-3f
#define W256_2 1.52587890625e-5f
#define W256_3 5.9604644775390625e-8f
#define K1LAST 0.3333282470703125f

// ---------- DPP cross-lane helpers (VALU pipe, no LDS) ----------
template<int CTRL, int RMASK>
__device__ __forceinline__ float dpp_add(float v) {
  int m = __builtin_amdgcn_update_dpp(0, __builtin_bit_cast(int, v), CTRL, RMASK, 0xf, false);
  return v + __builtin_bit_cast(float, m);
}
// full-wave sum; total lands in lane 63
__device__ __forceinline__ float wave_sum(float v) {
  v = dpp_add<0x111, 0xf>(v);   // row_shr:1
  v = dpp_add<0x112, 0xf>(v);   // row_shr:2
  v = dpp_add<0x114, 0xf>(v);   // row_shr:4
  v = dpp_add<0x118, 0xf>(v);   // row_shr:8
  v = dpp_add<0x142, 0xa>(v);   // row_bcast:15 -> rows 1,3
  v = dpp_add<0x143, 0xc>(v);   // row_bcast:31 -> rows 2,3
  return v;
}
// wave shift; invalid boundary lane receives `oldv`
template<int CTRL>
__device__ __forceinline__ float dpp_shift(float oldv, float v) {
  int m = __builtin_amdgcn_update_dpp(__builtin_bit_cast(int, oldv),
                                      __builtin_bit_cast(int, v), CTRL, 0xf, 0xf, false);
  return __builtin_bit_cast(float, m);
}

// ---------- setup-only: 2-barrier LDS tree reduce of 9 partials ----------
__device__ __forceinline__ void block_reduce9(const float pq[MM], float* __restrict__ s_part,
                                              float* __restrict__ dest, int destStride,
                                              int identCol, int t) {
#pragma unroll
  for (int m = 0; m < MM; ++m) s_part[m * NT + t] = pq[m];
  __syncthreads();
  const int wave = t >> 6, lane = t & 63;
  for (int m = wave; m < MM; m += NT / 64) {
    float s = 0.f;
#pragma unroll
    for (int k = 0; k < NT / 64; ++k) s += s_part[m * NT + lane + 64 * k];
#pragma unroll
    for (int off = 32; off; off >>= 1) s += __shfl_xor(s, off, 64);
    if (lane == 0) dest[m * destStride] = s + ((m == identCol) ? 1.f : 0.f);
  }
  __syncthreads();
}

// ---------- cyclic tridiagonal solve M p = r, split at the barrier ----------
// M = 25I - 10(P+P^T) = 5(2I-S+)(2I-S-); local scans + seed publish pre-barrier,
// carry reconstruction + finalize post-barrier. Truncation ~2^-32.
__device__ __forceinline__ void solveM_pre(const float r[EPT], float pl0[EPT],
                                           float2* __restrict__ s_sc, int t) {
  float yl[EPT];
  yl[EPT - 1] = r[EPT - 1] * 0.1f;
#pragma unroll
  for (int j = EPT - 2; j >= 0; --j) yl[j] = fmaf(0.5f, yl[j + 1], r[j] * 0.1f);
  pl0[0] = 0.5f * yl[0];
#pragma unroll
  for (int j = 1; j < EPT; ++j) pl0[j] = 0.5f * (yl[j] + pl0[j - 1]);
  s_sc[t] = make_float2(yl[0], pl0[EPT - 1]);
}

__device__ __forceinline__ void solveM_post(const float pl0[EPT], float p[EPT],
                                            const float2* __restrict__ s_sc, int t) {
  const float K1[EPT] = {0.001953125f, 0.0048828125f, 0.01025390625f, 0.020751953125f,
                         0.0416259765625f, 0.08331298828125f, 0.166656494140625f,
                         0.3333282470703125f};
  float2 g[9];
#pragma unroll
  for (int k = 0; k < 9; ++k) g[k] = s_sc[(t + k - 4) & (NT - 1)];
  float c = fmaf(W256_3, g[8].x, fmaf(W256_2, g[7].x, fmaf(W256_1, g[6].x, g[5].x)));
  float s1 = fmaf(W256_3, g[0].y, fmaf(W256_2, g[1].y, fmaf(W256_1, g[2].y, g[3].y)));
  float s2 = g[4].x;
  s2 = fmaf(W256_1, g[3].x + g[5].x, s2);
  s2 = fmaf(W256_2, g[2].x + g[6].x, s2);
  s2 = fmaf(W256_3, g[1].x + g[7].x, s2);
  float c2 = fmaf(K1LAST, s2, s1);
  float f2 = 0.5f;
#pragma unroll
  for (int j = 0; j < EPT; ++j) {
    p[j] = fmaf(c2, f2, fmaf(c, K1[j], pl0[j]));
    f2 *= 0.5f;
  }
}

__device__ __forceinline__ void solveM_full(const float r[EPT], float p[EPT],
                                            float2* __restrict__ s_sc, int t) {
  float pl0[EPT];
  solveM_pre(r, pl0, s_sc, t);
  __syncthreads();
  solveM_post(pl0, p, s_sc, t);
}

__global__ void __launch_bounds__(NT, 2)
admm_kernel(const float* __restrict__ tg, const float* __restrict__ Ag,
            const float* __restrict__ x0, float* __restrict__ out) {
  __shared__ float s_part[MM * NT];          // setup only
  __shared__ float2 s_sc[NT];
  __shared__ float2 s_sc2[NT];               // setup ping-pong
  __shared__ __align__(16) float s_wq[8][12];// per-wave zeta sums
  __shared__ float s_q[MM];
  __shared__ float s_S[MM * MM];
  __shared__ float s_Sinv[MM * MM];
  __shared__ float s_L[MM * MM];
  __shared__ float s_edge[8][2];             // [wave][0]=x[first], [1]=x[last]

  const int t = threadIdx.x;
  const int base = t * EPT;
  const int lane = t & 63, wave = t >> 6;

  // ---- load A slice ----
  float A[MM][EPT];
#pragma unroll
  for (int m = 0; m < MM; ++m) {
    float4 a0 = *(const float4*)(Ag + m * NN + base);
    float4 a1 = *(const float4*)(Ag + m * NN + base + 4);
    A[m][0] = a0.x; A[m][1] = a0.y; A[m][2] = a0.z; A[m][3] = a0.w;
    A[m][4] = a1.x; A[m][5] = a1.y; A[m][6] = a1.z; A[m][7] = a1.w;
  }

  // ---- load x0, target ----
  float x[EPT], tgt[EPT];
  {
    float4 v0 = *(const float4*)(x0 + base);
    float4 v1 = *(const float4*)(x0 + base + 4);
    x[0] = v0.x; x[1] = v0.y; x[2] = v0.z; x[3] = v0.w;
    x[4] = v1.x; x[5] = v1.y; x[6] = v1.z; x[7] = v1.w;
    float4 t0 = *(const float4*)(tg + base);
    float4 t1 = *(const float4*)(tg + base + 4);
    tgt[0] = t0.x; tgt[1] = t0.y; tgt[2] = t0.z; tgt[3] = t0.w;
    tgt[4] = t1.x; tgt[5] = t1.y; tgt[6] = t1.z; tgt[7] = t1.w;
  }
  if (lane == 0)  s_edge[wave][0] = x[0];
  if (lane == 63) s_edge[wave][1] = x[7];

  // ---- b = A @ target ----
  float pq[MM];
#pragma unroll
  for (int m = 0; m < MM; ++m) {
    float s = 0.f;
#pragma unroll
    for (int j = 0; j < EPT; ++j) s = fmaf(A[m][j], tgt[j], s);
    pq[m] = s;
  }
  block_reduce9(pq, s_part, s_q, 1, -1, t);

  // ---- bA = b @ A ----
  float bA[EPT];
  {
    float bv[MM];
#pragma unroll
    for (int m = 0; m < MM; ++m) bv[m] = s_q[m];
#pragma unroll
    for (int j = 0; j < EPT; ++j) {
      float s = 0.f;
#pragma unroll
      for (int m = 0; m < MM; ++m) s = fmaf(bv[m], A[m][j], s);
      bA[j] = s;
    }
  }

  // ---- S = I9 + A M^-1 A^T, one column at a time (no G storage) ----
#pragma unroll 1
  for (int mcol = 0; mcol < MM; ++mcol) {
    float rin[EPT], gcol[EPT];
#pragma unroll
    for (int j = 0; j < EPT; ++j) rin[j] = A[mcol][j];
    solveM_full(rin, gcol, (mcol & 1) ? s_sc2 : s_sc, t);
#pragma unroll
    for (int k = 0; k < MM; ++k) {
      float s = 0.f;
#pragma unroll
      for (int j = 0; j < EPT; ++j) s = fmaf(A[k][j], gcol[j], s);
      pq[k] = s;
    }
    block_reduce9(pq, s_part, &s_S[mcol], MM, mcol, t);
  }

  // ---- Sinv via wave-parallel Gauss-Jordan (lanes 0..8 of wave 0) ----
  if (t < 64) {
    float row[2 * MM];
#pragma unroll
    for (int j = 0; j < MM; ++j) row[j] = (t < MM) ? s_S[t * MM + j] : 0.f;
#pragma unroll
    for (int j = 0; j < MM; ++j) row[MM + j] = (j == t) ? 1.f : 0.f;
#pragma unroll
    for (int pp = 0; pp < MM; ++pp) {
      float pr[2 * MM];
#pragma unroll
      for (int j = 0; j < 2 * MM; ++j) pr[j] = __shfl(row[j], pp, 64);
      float rpiv = 1.f / pr[pp];
      float fct = row[pp] * rpiv;
#pragma unroll
      for (int j = 0; j < 2 * MM; ++j)
        row[j] = (t == pp) ? pr[j] * rpiv : fmaf(-fct, pr[j], row[j]);
    }
    if (t < MM) {
#pragma unroll
      for (int j = 0; j < MM; ++j) s_Sinv[t * MM + j] = row[MM + j];
    }
  }
  __syncthreads();

  // ---- Cholesky Sinv = L L^T (wave 0, lane i owns row i) ----
  if (t < 64) {
    float row[MM];
#pragma unroll
    for (int j = 0; j < MM; ++j) row[j] = (t < MM) ? s_Sinv[t * MM + j] : 0.f;
#pragma unroll
    for (int k = 0; k < MM; ++k) {
      float dk = __shfl(row[k], k, 64);
      float inv = 1.f / sqrtf(dk);
      row[k] *= inv;
#pragma unroll
      for (int jj = k + 1; jj < MM; ++jj) {
        float ljk = __shfl(row[k], jj, 64);   // L[jj][k]
        row[jj] = fmaf(-row[k], ljk, row[jj]);
      }
    }
    if (t < MM) {
#pragma unroll
      for (int j = 0; j < MM; ++j) s_L[t * MM + j] = (t >= j) ? row[j] : 0.f;
    }
  }
  __syncthreads();

  // ---- GH = M^-1 (A^T L): rhs_m = sum_k A[k] L[k][m], then solve ----
  float GH[MM][EPT];
#pragma unroll 1
  for (int m = 0; m < MM; ++m) {
    float lcol[MM];
#pragma unroll
    for (int k = 0; k < MM; ++k) lcol[k] = s_L[k * MM + m];
    float rhs[EPT];
#pragma unroll
    for (int j = 0; j < EPT; ++j) {
      float s = 0.f;
#pragma unroll
      for (int k = 0; k < MM; ++k) s = fmaf(A[k][j], lcol[k], s);  // L[k][m]=0 for k<m
      rhs[j] = s;
    }
    float gh[EPT];
    solveM_full(rhs, gh, (m & 1) ? s_sc2 : s_sc, t);
#pragma unroll
    for (int j = 0; j < EPT; ++j) GH[m][j] = gh[j];
  }

  // ---- ADMM iterations: 2 barriers each ----
  float eta[EPT], tau[EPT];
#pragma unroll
  for (int j = 0; j < EPT; ++j) { eta[j] = 0.f; tau[j] = 0.f; }
  float u7prev = 0.f, w7prev = 0.f;

#pragma unroll 1
  for (int it = 0; it < NIT; ++it) {
    // --- phase 0: neighbors via DPP wave-shift, edge lanes via LDS ---
    float oldm = 0.f, oldn = 0.f;
    if (lane == 0)  oldm = s_edge[(wave + 7) & 7][1];
    if (lane == 63) oldn = s_edge[(wave + 1) & 7][0];
    float xm1 = dpp_shift<0x138>(oldm, x[7]);   // wave_shr1: lane i <- lane i-1
    if (it) {
      float xn8 = dpp_shift<0x130>(oldn, x[0]); // wave_shl1: lane i <- lane i+1
      eta[7] = fmaf(10.f, (xn8 - x[7]) - u7prev, eta[7]);
      tau[7] = fmaf(5.f, x[7] - w7prev, tau[7]);
    }
    // --- u, w, r ---
    float u[EPT], w[EPT], r[EPT];
#pragma unroll
    for (int j = 0; j < EPT; ++j) {
      float xprev = (j == 0) ? xm1 : x[j - 1];
      float v = xprev - x[j] + eta[j] * 0.1f;
      float a = fabsf(v) - 1e-5f;
      u[j] = (a > 0.f) ? copysignf(a, v) : 0.f;
      w[j] = fmaxf(fmaf(tau[j], 0.2f, x[j]), 0.f);
      r[j] = bA[j] + 10.f * u[j] - eta[j] + 5.f * w[j] - tau[j];
    }
    // --- zeta partials (from r directly!) + DPP wave reduce ---
    float zp[MM];
#pragma unroll
    for (int m = 0; m < MM; ++m) {
      float s = 0.f;
#pragma unroll
      for (int j = 0; j < EPT; ++j) s = fmaf(GH[m][j], r[j], s);
      zp[m] = wave_sum(s);
    }
    if (lane == 63) {
      *(float4*)&s_wq[wave][0] = make_float4(zp[0], zp[1], zp[2], zp[3]);
      *(float4*)&s_wq[wave][4] = make_float4(zp[4], zp[5], zp[6], zp[7]);
      s_wq[wave][8] = zp[8];
    }
    // --- solveM local scans + seed publish ---
    float pl0[EPT];
    solveM_pre(r, pl0, s_sc, t);
    __syncthreads();                            // BARRIER A
    // --- finish solve, combine zeta across waves ---
    float p[EPT];
    solveM_post(pl0, p, s_sc, t);
    float z[MM];
    {
      float4 a0 = *(const float4*)&s_wq[0][0];
      float4 a1 = *(const float4*)&s_wq[0][4];
      float  a2 = s_wq[0][8];
      z[0] = a0.x; z[1] = a0.y; z[2] = a0.z; z[3] = a0.w;
      z[4] = a1.x; z[5] = a1.y; z[6] = a1.z; z[7] = a1.w; z[8] = a2;
#pragma unroll
      for (int wv = 1; wv < 8; ++wv) {
        float4 b0 = *(const float4*)&s_wq[wv][0];
        float4 b1 = *(const float4*)&s_wq[wv][4];
        float  b2 = s_wq[wv][8];
        z[0] += b0.x; z[1] += b0.y; z[2] += b0.z; z[3] += b0.w;
        z[4] += b1.x; z[5] += b1.y; z[6] += b1.z; z[7] += b1.w; z[8] += b2;
      }
    }
    // --- x_new = p - GH z ---
    float xn[EPT];
#pragma unroll
    for (int j = 0; j < EPT; ++j) {
      float s = p[j];
#pragma unroll
      for (int m = 0; m < MM; ++m) s = fmaf(-GH[m][j], z[m], s);
      xn[j] = s;
    }
    if (lane == 0)  s_edge[wave][0] = xn[0];
    if (lane == 63) s_edge[wave][1] = xn[7];
    // --- duals j=0..6 now; j=7 deferred to next iteration ---
#pragma unroll
    for (int j = 0; j < EPT - 1; ++j) {
      eta[j] = fmaf(10.f, (xn[j + 1] - xn[j]) - u[j], eta[j]);
      tau[j] = fmaf(5.f, xn[j] - w[j], tau[j]);
    }
    u7prev = u[7]; w7prev = w[7];
#pragma unroll
    for (int j = 0; j < EPT; ++j) x[j] = xn[j];
    __syncthreads();                            // BARRIER B
  }

  // ---- output ----
  float4 o0, o1;
  o0.x = x[0]; o0.y = x[1]; o0.z = x[2]; o0.w = x[3];
  o1.x = x[4]; o1.y = x[5]; o1.z = x[6]; o1.w = x[7];
  *(float4*)(out + base) = o0;
  *(float4*)(out + base + 4) = o1;
}

extern "C" void kernel_launch(void* const* d_in, const int* in_sizes, int n_in,
                              void* d_out, int out_size, void* d_ws, size_t ws_size,
                              hipStream_t stream) {
  const float* target = (const float*)d_in[0];
  const float* A      = (const float*)d_in[1];
  const float* x0     = (const float*)d_in[2];
  admm_kernel<<<1, NT, 0, stream>>>(target, A, x0, (float*)d_out);
}

// Round 4
// 122.644 us; speedup vs baseline: 4.0491x; 4.0491x over previous
//
#include <hip/hip_runtime.h>
#include <math.h>

#define NT 512      // 8 waves, single block, single CU
#define EPT 8       // NT*EPT = 4096
#define NN 4096
#define MM 9
#define NIT 50

// geometric carry weights (per-thread hop decay 2^-8)
#define W256_1 3.90625e-3f
#define W256_2 1.52587890625e-5f
#define W256_3 5.9604644775390625e-8f
#define K1LAST 0.3333282470703125f

// ---------- DPP cross-lane helpers (VALU pipe, no LDS) ----------
template<int CTRL, int RMASK>
__device__ __forceinline__ float dpp_add(float v) {
  int m = __builtin_amdgcn_update_dpp(0, __builtin_bit_cast(int, v), CTRL, RMASK, 0xf, false);
  return v + __builtin_bit_cast(float, m);
}
// full-wave sum; total lands in lane 63
__device__ __forceinline__ float wave_sum(float v) {
  v = dpp_add<0x111, 0xf>(v);   // row_shr:1
  v = dpp_add<0x112, 0xf>(v);   // row_shr:2
  v = dpp_add<0x114, 0xf>(v);   // row_shr:4
  v = dpp_add<0x118, 0xf>(v);   // row_shr:8
  v = dpp_add<0x142, 0xa>(v);   // row_bcast:15 -> rows 1,3
  v = dpp_add<0x143, 0xc>(v);   // row_bcast:31 -> rows 2,3
  return v;
}
// wave shift; invalid boundary lane receives `oldv`
template<int CTRL>
__device__ __forceinline__ float dpp_shift(float oldv, float v) {
  int m = __builtin_amdgcn_update_dpp(__builtin_bit_cast(int, oldv),
                                      __builtin_bit_cast(int, v), CTRL, 0xf, 0xf, false);
  return __builtin_bit_cast(float, m);
}

// ---------- setup-only: 2-barrier LDS tree reduce of 9 partials ----------
__device__ __forceinline__ void block_reduce9(const float pq[MM], float* __restrict__ s_part,
                                              float* __restrict__ dest, int destStride,
                                              int identCol, int t) {
#pragma unroll
  for (int m = 0; m < MM; ++m) s_part[m * NT + t] = pq[m];
  __syncthreads();
  const int wave = t >> 6, lane = t & 63;
  for (int m = wave; m < MM; m += NT / 64) {
    float s = 0.f;
#pragma unroll
    for (int k = 0; k < NT / 64; ++k) s += s_part[m * NT + lane + 64 * k];
#pragma unroll
    for (int off = 32; off; off >>= 1) s += __shfl_xor(s, off, 64);
    if (lane == 0) dest[m * destStride] = s + ((m == identCol) ? 1.f : 0.f);
  }
  __syncthreads();
}

// ---------- cyclic tridiagonal solve M p = r, split at the barrier ----------
// M = 25I - 10(P+P^T) = 5(2I-S+)(2I-S-); local scans + seed publish pre-barrier,
// carry reconstruction + finalize post-barrier. Truncation ~2^-32.
__device__ __forceinline__ void solveM_pre(const float r[EPT], float pl0[EPT],
                                           float2* __restrict__ s_sc, int t) {
  float yl[EPT];
  yl[EPT - 1] = r[EPT - 1] * 0.1f;
#pragma unroll
  for (int j = EPT - 2; j >= 0; --j) yl[j] = fmaf(0.5f, yl[j + 1], r[j] * 0.1f);
  pl0[0] = 0.5f * yl[0];
#pragma unroll
  for (int j = 1; j < EPT; ++j) pl0[j] = 0.5f * (yl[j] + pl0[j - 1]);
  s_sc[t] = make_float2(yl[0], pl0[EPT - 1]);
}

__device__ __forceinline__ void solveM_post(const float pl0[EPT], float p[EPT],
                                            const float2* __restrict__ s_sc, int t) {
  const float K1[EPT] = {0.001953125f, 0.0048828125f, 0.01025390625f, 0.020751953125f,
                         0.0416259765625f, 0.08331298828125f, 0.166656494140625f,
                         0.3333282470703125f};
  float2 g[9];
#pragma unroll
  for (int k = 0; k < 9; ++k) g[k] = s_sc[(t + k - 4) & (NT - 1)];
  float c = fmaf(W256_3, g[8].x, fmaf(W256_2, g[7].x, fmaf(W256_1, g[6].x, g[5].x)));
  float s1 = fmaf(W256_3, g[0].y, fmaf(W256_2, g[1].y, fmaf(W256_1, g[2].y, g[3].y)));
  float s2 = g[4].x;
  s2 = fmaf(W256_1, g[3].x + g[5].x, s2);
  s2 = fmaf(W256_2, g[2].x + g[6].x, s2);
  s2 = fmaf(W256_3, g[1].x + g[7].x, s2);
  float c2 = fmaf(K1LAST, s2, s1);
  float f2 = 0.5f;
#pragma unroll
  for (int j = 0; j < EPT; ++j) {
    p[j] = fmaf(c2, f2, fmaf(c, K1[j], pl0[j]));
    f2 *= 0.5f;
  }
}

__device__ __forceinline__ void solveM_full(const float r[EPT], float p[EPT],
                                            float2* __restrict__ s_sc, int t) {
  float pl0[EPT];
  solveM_pre(r, pl0, s_sc, t);
  __syncthreads();
  solveM_post(pl0, p, s_sc, t);
}

__global__ void __launch_bounds__(NT, 2)
admm_kernel(const float* __restrict__ tg, const float* __restrict__ Ag,
            const float* __restrict__ x0, float* __restrict__ out) {
  __shared__ float s_part[MM * NT];          // setup only
  __shared__ float2 s_sc[NT];
  __shared__ float2 s_sc2[NT];               // setup ping-pong
  __shared__ __align__(16) float s_wq[8][12];// per-wave zeta sums
  __shared__ float s_q[MM];
  __shared__ float s_S[MM * MM];
  __shared__ float s_Sinv[MM * MM];
  __shared__ float s_L[MM * MM];
  __shared__ float s_edge[8][2];             // [wave][0]=x[first], [1]=x[last]

  const int t = threadIdx.x;
  const int base = t * EPT;
  const int lane = t & 63, wave = t >> 6;

  // ---- load A slice (REGISTER-RESIDENT: every access below is compile-time-indexed) ----
  float A[MM][EPT];
#pragma unroll
  for (int m = 0; m < MM; ++m) {
    float4 a0 = *(const float4*)(Ag + m * NN + base);
    float4 a1 = *(const float4*)(Ag + m * NN + base + 4);
    A[m][0] = a0.x; A[m][1] = a0.y; A[m][2] = a0.z; A[m][3] = a0.w;
    A[m][4] = a1.x; A[m][5] = a1.y; A[m][6] = a1.z; A[m][7] = a1.w;
  }

  // ---- load x0, target ----
  float x[EPT], tgt[EPT];
  {
    float4 v0 = *(const float4*)(x0 + base);
    float4 v1 = *(const float4*)(x0 + base + 4);
    x[0] = v0.x; x[1] = v0.y; x[2] = v0.z; x[3] = v0.w;
    x[4] = v1.x; x[5] = v1.y; x[6] = v1.z; x[7] = v1.w;
    float4 t0 = *(const float4*)(tg + base);
    float4 t1 = *(const float4*)(tg + base + 4);
    tgt[0] = t0.x; tgt[1] = t0.y; tgt[2] = t0.z; tgt[3] = t0.w;
    tgt[4] = t1.x; tgt[5] = t1.y; tgt[6] = t1.z; tgt[7] = t1.w;
  }
  if (lane == 0)  s_edge[wave][0] = x[0];
  if (lane == 63) s_edge[wave][1] = x[7];

  // ---- b = A @ target ----
  float pq[MM];
#pragma unroll
  for (int m = 0; m < MM; ++m) {
    float s = 0.f;
#pragma unroll
    for (int j = 0; j < EPT; ++j) s = fmaf(A[m][j], tgt[j], s);
    pq[m] = s;
  }
  block_reduce9(pq, s_part, s_q, 1, -1, t);

  // ---- bA = b @ A ----
  float bA[EPT];
  {
    float bv[MM];
#pragma unroll
    for (int m = 0; m < MM; ++m) bv[m] = s_q[m];
#pragma unroll
    for (int j = 0; j < EPT; ++j) {
      float s = 0.f;
#pragma unroll
      for (int m = 0; m < MM; ++m) s = fmaf(bv[m], A[m][j], s);
      bA[j] = s;
    }
  }

  // ---- S = I9 + A M^-1 A^T, one column at a time ----
  // FULLY UNROLLED (rule #20): runtime mcol would demote A[] to scratch.
#pragma unroll
  for (int mcol = 0; mcol < MM; ++mcol) {
    float rin[EPT], gcol[EPT];
#pragma unroll
    for (int j = 0; j < EPT; ++j) rin[j] = A[mcol][j];
    solveM_full(rin, gcol, (mcol & 1) ? s_sc2 : s_sc, t);
#pragma unroll
    for (int k = 0; k < MM; ++k) {
      float s = 0.f;
#pragma unroll
      for (int j = 0; j < EPT; ++j) s = fmaf(A[k][j], gcol[j], s);
      pq[k] = s;
    }
    block_reduce9(pq, s_part, &s_S[mcol], MM, mcol, t);
  }

  // ---- Sinv via wave-parallel Gauss-Jordan (lanes 0..8 of wave 0) ----
  if (t < 64) {
    float row[2 * MM];
#pragma unroll
    for (int j = 0; j < MM; ++j) row[j] = (t < MM) ? s_S[t * MM + j] : 0.f;
#pragma unroll
    for (int j = 0; j < MM; ++j) row[MM + j] = (j == t) ? 1.f : 0.f;
#pragma unroll
    for (int pp = 0; pp < MM; ++pp) {
      float pr[2 * MM];
#pragma unroll
      for (int j = 0; j < 2 * MM; ++j) pr[j] = __shfl(row[j], pp, 64);
      float rpiv = 1.f / pr[pp];
      float fct = row[pp] * rpiv;
#pragma unroll
      for (int j = 0; j < 2 * MM; ++j)
        row[j] = (t == pp) ? pr[j] * rpiv : fmaf(-fct, pr[j], row[j]);
    }
    if (t < MM) {
#pragma unroll
      for (int j = 0; j < MM; ++j) s_Sinv[t * MM + j] = row[MM + j];
    }
  }
  __syncthreads();

  // ---- Cholesky Sinv = L L^T (wave 0, lane i owns row i) ----
  if (t < 64) {
    float row[MM];
#pragma unroll
    for (int j = 0; j < MM; ++j) row[j] = (t < MM) ? s_Sinv[t * MM + j] : 0.f;
#pragma unroll
    for (int k = 0; k < MM; ++k) {
      float dk = __shfl(row[k], k, 64);
      float inv = 1.f / sqrtf(dk);
      row[k] *= inv;
#pragma unroll
      for (int jj = k + 1; jj < MM; ++jj) {
        float ljk = __shfl(row[k], jj, 64);   // L[jj][k]
        row[jj] = fmaf(-row[k], ljk, row[jj]);
      }
    }
    if (t < MM) {
#pragma unroll
      for (int j = 0; j < MM; ++j) s_L[t * MM + j] = (t >= j) ? row[j] : 0.f;
    }
  }
  __syncthreads();

  // ---- GH = M^-1 (A^T L): rhs_m = sum_k A[k] L[k][m], then solve ----
  // FULLY UNROLLED (rule #20): runtime m writes would demote GH[] to scratch.
  float GH[MM][EPT];
#pragma unroll
  for (int m = 0; m < MM; ++m) {
    float lcol[MM];
#pragma unroll
    for (int k = 0; k < MM; ++k) lcol[k] = s_L[k * MM + m];
    float rhs[EPT];
#pragma unroll
    for (int j = 0; j < EPT; ++j) {
      float s = 0.f;
#pragma unroll
      for (int k = 0; k < MM; ++k) s = fmaf(A[k][j], lcol[k], s);  // L[k][m]=0 for k<m
      rhs[j] = s;
    }
    float gh[EPT];
    solveM_full(rhs, gh, (m & 1) ? s_sc2 : s_sc, t);
#pragma unroll
    for (int j = 0; j < EPT; ++j) GH[m][j] = gh[j];
  }

  // ---- ADMM iterations: 2 barriers each; persistent regs = GH(72)+state(32) ----
  float eta[EPT], tau[EPT];
#pragma unroll
  for (int j = 0; j < EPT; ++j) { eta[j] = 0.f; tau[j] = 0.f; }
  float u7prev = 0.f, w7prev = 0.f;

#pragma unroll 1
  for (int it = 0; it < NIT; ++it) {
    // --- neighbors via DPP wave-shift, edge lanes via LDS ---
    float oldm = 0.f, oldn = 0.f;
    if (lane == 0)  oldm = s_edge[(wave + 7) & 7][1];
    if (lane == 63) oldn = s_edge[(wave + 1) & 7][0];
    float xm1 = dpp_shift<0x138>(oldm, x[7]);   // wave_shr1: lane i <- lane i-1
    if (it) {
      float xn8 = dpp_shift<0x130>(oldn, x[0]); // wave_shl1: lane i <- lane i+1
      eta[7] = fmaf(10.f, (xn8 - x[7]) - u7prev, eta[7]);
      tau[7] = fmaf(5.f, x[7] - w7prev, tau[7]);
    }
    // --- u, w, r ---
    float u[EPT], w[EPT], r[EPT];
#pragma unroll
    for (int j = 0; j < EPT; ++j) {
      float xprev = (j == 0) ? xm1 : x[j - 1];
      float v = xprev - x[j] + eta[j] * 0.1f;
      float a = fabsf(v) - 1e-5f;
      u[j] = (a > 0.f) ? copysignf(a, v) : 0.f;
      w[j] = fmaxf(fmaf(tau[j], 0.2f, x[j]), 0.f);
      r[j] = bA[j] + 10.f * u[j] - eta[j] + 5.f * w[j] - tau[j];
    }
    // --- zeta partials (from r directly) + DPP wave reduce ---
    float zp[MM];
#pragma unroll
    for (int m = 0; m < MM; ++m) {
      float s = 0.f;
#pragma unroll
      for (int j = 0; j < EPT; ++j) s = fmaf(GH[m][j], r[j], s);
      zp[m] = wave_sum(s);
    }
    if (lane == 63) {
      *(float4*)&s_wq[wave][0] = make_float4(zp[0], zp[1], zp[2], zp[3]);
      *(float4*)&s_wq[wave][4] = make_float4(zp[4], zp[5], zp[6], zp[7]);
      s_wq[wave][8] = zp[8];
    }
    // --- solveM local scans + seed publish ---
    float pl0[EPT];
    solveM_pre(r, pl0, s_sc, t);
    __syncthreads();                            // BARRIER A
    // --- finish solve, combine zeta across waves ---
    float p[EPT];
    solveM_post(pl0, p, s_sc, t);
    float z[MM];
    {
      float4 a0 = *(const float4*)&s_wq[0][0];
      float4 a1 = *(const float4*)&s_wq[0][4];
      float  a2 = s_wq[0][8];
      z[0] = a0.x; z[1] = a0.y; z[2] = a0.z; z[3] = a0.w;
      z[4] = a1.x; z[5] = a1.y; z[6] = a1.z; z[7] = a1.w; z[8] = a2;
#pragma unroll
      for (int wv = 1; wv < 8; ++wv) {
        float4 b0 = *(const float4*)&s_wq[wv][0];
        float4 b1 = *(const float4*)&s_wq[wv][4];
        float  b2 = s_wq[wv][8];
        z[0] += b0.x; z[1] += b0.y; z[2] += b0.z; z[3] += b0.w;
        z[4] += b1.x; z[5] += b1.y; z[6] += b1.z; z[7] += b1.w; z[8] += b2;
      }
    }
    // --- x_new = p - GH z ---
    float xn[EPT];
#pragma unroll
    for (int j = 0; j < EPT; ++j) {
      float s = p[j];
#pragma unroll
      for (int m = 0; m < MM; ++m) s = fmaf(-GH[m][j], z[m], s);
      xn[j] = s;
    }
    if (lane == 0)  s_edge[wave][0] = xn[0];
    if (lane == 63) s_edge[wave][1] = xn[7];
    // --- duals j=0..6 now; j=7 deferred to next iteration ---
#pragma unroll
    for (int j = 0; j < EPT - 1; ++j) {
      eta[j] = fmaf(10.f, (xn[j + 1] - xn[j]) - u[j], eta[j]);
      tau[j] = fmaf(5.f, xn[j] - w[j], tau[j]);
    }
    u7prev = u[7]; w7prev = w[7];
#pragma unroll
    for (int j = 0; j < EPT; ++j) x[j] = xn[j];
    __syncthreads();                            // BARRIER B
  }

  // ---- output ----
  float4 o0, o1;
  o0.x = x[0]; o0.y = x[1]; o0.z = x[2]; o0.w = x[3];
  o1.x = x[4]; o1.y = x[5]; o1.z = x[6]; o1.w = x[7];
  *(float4*)(out + base) = o0;
  *(float4*)(out + base + 4) = o1;
}

extern "C" void kernel_launch(void* const* d_in, const int* in_sizes, int n_in,
                              void* d_out, int out_size, void* d_ws, size_t ws_size,
                              hipStream_t stream) {
  const float* target = (const float*)d_in[0];
  const float* A      = (const float*)d_in[1];
  const float* x0     = (const float*)d_in[2];
  admm_kernel<<<1, NT, 0, stream>>>(target, A, x0, (float*)d_out);
}

// Round 6
// 106.499 us; speedup vs baseline: 4.6629x; 1.1516x over previous
//
#include <hip/hip_runtime.h>
#include <math.h>

#define NT 512      // 8 waves, single block, single CU
#define EPT 8       // NT*EPT = 4096
#define NN 4096
#define MM 9
#define NIT 50

#define LAM  3.90625e-3f        // 2^-8 (per-thread carry decay)
#define LAM2 1.52587890625e-5f  // 2^-16
#define K1LAST 0.3333282470703125f

// ---------- DPP cross-lane helpers (VALU pipe, no LDS) ----------
template<int CTRL, int RMASK>
__device__ __forceinline__ float dpp_add(float v) {
  int m = __builtin_amdgcn_update_dpp(0, __builtin_bit_cast(int, v), CTRL, RMASK, 0xf, false);
  return v + __builtin_bit_cast(float, m);
}
// full-wave sum; total lands in lane 63
__device__ __forceinline__ float wave_sum(float v) {
  v = dpp_add<0x111, 0xf>(v);   // row_shr:1
  v = dpp_add<0x112, 0xf>(v);   // row_shr:2
  v = dpp_add<0x114, 0xf>(v);   // row_shr:4
  v = dpp_add<0x118, 0xf>(v);   // row_shr:8
  v = dpp_add<0x142, 0xa>(v);   // row_bcast:15 -> rows 1,3
  v = dpp_add<0x143, 0xc>(v);   // row_bcast:31 -> rows 2,3
  return v;
}
// wave shift; invalid boundary lane receives `oldv`
template<int CTRL>
__device__ __forceinline__ float dpp_shift(float oldv, float v) {
  int m = __builtin_amdgcn_update_dpp(__builtin_bit_cast(int, oldv),
                                      __builtin_bit_cast(int, v), CTRL, 0xf, 0xf, false);
  return __builtin_bit_cast(float, m);
}
// broadcast lane l (uniform literal) -> SGPR
__device__ __forceinline__ float bcast_lane(float v, int l) {
  return __builtin_bit_cast(float, __builtin_amdgcn_readlane(__builtin_bit_cast(int, v), l));
}

// ---------- cyclic tridiagonal solve M p = r, split at the barrier ----------
// M = 25I - 10(P+P^T) = 5(2I-S+)(2I-S-); local scans + seed publish pre-barrier,
// carry reconstruction + finalize post-barrier. Truncation ~2^-24 (vs 3.6e-2 tol).
__device__ __forceinline__ void solveM_pre(const float r[EPT], float pl0[EPT],
                                           float2* __restrict__ s_sc, int t) {
  float yl[EPT];
  yl[EPT - 1] = r[EPT - 1] * 0.1f;
#pragma unroll
  for (int j = EPT - 2; j >= 0; --j) yl[j] = fmaf(0.5f, yl[j + 1], r[j] * 0.1f);
  pl0[0] = 0.5f * yl[0];
#pragma unroll
  for (int j = 1; j < EPT; ++j) pl0[j] = 0.5f * (yl[j] + pl0[j - 1]);
  s_sc[t] = make_float2(yl[0], pl0[EPT - 1]);
}

__device__ __forceinline__ void solveM_post(const float pl0[EPT], float p[EPT],
                                            const float2* __restrict__ s_sc, int t) {
  const float K1[EPT] = {0.001953125f, 0.0048828125f, 0.01025390625f, 0.020751953125f,
                         0.0416259765625f, 0.08331298828125f, 0.166656494140625f,
                         0.3333282470703125f};
  float2 g[7];
#pragma unroll
  for (int k = 0; k < 7; ++k) g[k] = s_sc[(t + k - 3) & (NT - 1)];
  // backward carry: c = sum_i lam^i yl0[t+1+i], i=0..2
  float c  = fmaf(LAM2, g[6].x, fmaf(LAM, g[5].x, g[4].x));
  // forward carry: s1 over pl0last[t-1-j], coupling s2 over yl0[t+k]
  float s1 = fmaf(LAM2, g[0].y, fmaf(LAM, g[1].y, g[2].y));
  float s2 = g[3].x;
  s2 = fmaf(LAM, g[2].x + g[4].x, s2);
  s2 = fmaf(LAM2, g[1].x + g[5].x, s2);
  float c2 = fmaf(K1LAST, s2, s1);
  float f2 = 0.5f;
#pragma unroll
  for (int j = 0; j < EPT; ++j) {
    p[j] = fmaf(c2, f2, fmaf(c, K1[j], pl0[j]));
    f2 *= 0.5f;
  }
}

__global__ void __launch_bounds__(NT, 2)
admm_kernel(const float* __restrict__ tg, const float* __restrict__ Ag,
            const float* __restrict__ x0, float* __restrict__ out) {
  __shared__ float2 s_sc[NT];
  __shared__ __align__(16) float s_wq[8][12];   // per-wave 9-partials
  __shared__ float s_S[MM * MM];
  __shared__ float s_L[MM * MM];
  __shared__ float s_edge[8][2];                // [wave][0]=x[first], [1]=x[last]

  const int t = threadIdx.x;
  const int base = t * EPT;
  const int lane = t & 63, wave = t >> 6;

  // ---- load A slice (register-resident; all accesses compile-time-indexed) ----
  float A[MM][EPT];
#pragma unroll
  for (int m = 0; m < MM; ++m) {
    float4 a0 = *(const float4*)(Ag + m * NN + base);
    float4 a1 = *(const float4*)(Ag + m * NN + base + 4);
    A[m][0] = a0.x; A[m][1] = a0.y; A[m][2] = a0.z; A[m][3] = a0.w;
    A[m][4] = a1.x; A[m][5] = a1.y; A[m][6] = a1.z; A[m][7] = a1.w;
  }

  // ---- load x0, target ----
  float x[EPT], tgt[EPT];
  {
    float4 v0 = *(const float4*)(x0 + base);
    float4 v1 = *(const float4*)(x0 + base + 4);
    x[0] = v0.x; x[1] = v0.y; x[2] = v0.z; x[3] = v0.w;
    x[4] = v1.x; x[5] = v1.y; x[6] = v1.z; x[7] = v1.w;
    float4 t0 = *(const float4*)(tg + base);
    float4 t1 = *(const float4*)(tg + base + 4);
    tgt[0] = t0.x; tgt[1] = t0.y; tgt[2] = t0.z; tgt[3] = t0.w;
    tgt[4] = t1.x; tgt[5] = t1.y; tgt[6] = t1.z; tgt[7] = t1.w;
  }
  if (lane == 0)  s_edge[wave][0] = x[0];
  if (lane == 63) s_edge[wave][1] = x[7];

  // ---- b = A @ target: DPP reduce + lane-combine + readlane -> SGPRs ----
  float pq[MM];
#pragma unroll
  for (int m = 0; m < MM; ++m) {
    float s = 0.f;
#pragma unroll
    for (int j = 0; j < EPT; ++j) s = fmaf(A[m][j], tgt[j], s);
    pq[m] = wave_sum(s);
  }
  if (lane == 63) {
    *(float4*)&s_wq[wave][0] = make_float4(pq[0], pq[1], pq[2], pq[3]);
    *(float4*)&s_wq[wave][4] = make_float4(pq[4], pq[5], pq[6], pq[7]);
    s_wq[wave][8] = pq[8];
  }
  __syncthreads();
  float bb[MM];
  {
    float zv = 0.f;
    if (lane < MM) {
#pragma unroll
      for (int wv = 0; wv < 8; ++wv) zv += s_wq[wv][lane];
    }
#pragma unroll
    for (int m = 0; m < MM; ++m) bb[m] = bcast_lane(zv, m);
  }
  float bA[EPT];
#pragma unroll
  for (int j = 0; j < EPT; ++j) {
    float s = 0.f;
#pragma unroll
    for (int m = 0; m < MM; ++m) s = fmaf(bb[m], A[m][j], s);
    bA[j] = s;
  }

  // ---- S = I9 + A M^-1 A^T, keeping G columns for the GH fold ----
  float G[MM][EPT];
#pragma unroll
  for (int mc = 0; mc < MM; ++mc) {
    float rin[EPT];
#pragma unroll
    for (int j = 0; j < EPT; ++j) rin[j] = A[mc][j];
    float pl0[EPT];
    solveM_pre(rin, pl0, s_sc, t);
    __syncthreads();
    float gcol[EPT];
    solveM_post(pl0, gcol, s_sc, t);
#pragma unroll
    for (int j = 0; j < EPT; ++j) G[mc][j] = gcol[j];
#pragma unroll
    for (int k = 0; k < MM; ++k) {
      float s = 0.f;
#pragma unroll
      for (int j = 0; j < EPT; ++j) s = fmaf(A[k][j], gcol[j], s);
      pq[k] = wave_sum(s);
    }
    if (lane == 63) {
      *(float4*)&s_wq[wave][0] = make_float4(pq[0], pq[1], pq[2], pq[3]);
      *(float4*)&s_wq[wave][4] = make_float4(pq[4], pq[5], pq[6], pq[7]);
      s_wq[wave][8] = pq[8];
    }
    __syncthreads();
    if (wave == 0 && lane < MM) {
      float s = 0.f;
#pragma unroll
      for (int wv = 0; wv < 8; ++wv) s += s_wq[wv][lane];
      s_S[lane * MM + mc] = s + ((lane == mc) ? 1.f : 0.f);
    }
  }

  // ---- Sinv (Gauss-Jordan) + Cholesky Sinv = L L^T, fused on wave 0 ----
  if (t < 64) {
    float row[2 * MM];
#pragma unroll
    for (int j = 0; j < MM; ++j) row[j] = (t < MM) ? s_S[t * MM + j] : 0.f;
#pragma unroll
    for (int j = 0; j < MM; ++j) row[MM + j] = (j == t) ? 1.f : 0.f;
#pragma unroll
    for (int pp = 0; pp < MM; ++pp) {
      float pr[2 * MM];
#pragma unroll
      for (int j = 0; j < 2 * MM; ++j) pr[j] = __shfl(row[j], pp, 64);
      float rpiv = 1.f / pr[pp];
      float fct = row[pp] * rpiv;
#pragma unroll
      for (int j = 0; j < 2 * MM; ++j)
        row[j] = (t == pp) ? pr[j] * rpiv : fmaf(-fct, pr[j], row[j]);
    }
    // rows of Sinv now in row[MM..2MM-1] (zeros for t>=MM); Cholesky in-register
    float crow[MM];
#pragma unroll
    for (int j = 0; j < MM; ++j) crow[j] = row[MM + j];
#pragma unroll
    for (int k = 0; k < MM; ++k) {
      float dk = __shfl(crow[k], k, 64);
      float inv = 1.f / sqrtf(dk);
      crow[k] *= inv;
#pragma unroll
      for (int jj = k + 1; jj < MM; ++jj) {
        float ljk = __shfl(crow[k], jj, 64);   // L[jj][k]
        crow[jj] = fmaf(-crow[k], ljk, crow[jj]);
      }
    }
    if (t < MM) {
#pragma unroll
      for (int j = 0; j < MM; ++j) s_L[t * MM + j] = (t >= j) ? crow[j] : 0.f;
    }
  }
  __syncthreads();

  // ---- GH[m] = sum_{k>=m} G[k] * L[k][m] (no extra solves; fully unrolled) ----
  float GH[MM][EPT];
#pragma unroll
  for (int m = 0; m < MM; ++m) {
    float lcol[MM];
#pragma unroll
    for (int k = 0; k < MM; ++k) lcol[k] = s_L[k * MM + m];
#pragma unroll
    for (int j = 0; j < EPT; ++j) {
      float s = 0.f;
#pragma unroll
      for (int k = 0; k < MM; ++k)
        if (k >= m) s = fmaf(G[k][j], lcol[k], s);
      GH[m][j] = s;
    }
  }

  // ---- ADMM iterations: 2 barriers each; z in SGPRs; in-place x ----
  float eta[EPT], tau[EPT];
#pragma unroll
  for (int j = 0; j < EPT; ++j) { eta[j] = 0.f; tau[j] = 0.f; }
  float u7prev = 0.f, w7prev = 0.f;

#pragma unroll 1
  for (int it = 0; it < NIT; ++it) {
    // --- neighbors via DPP wave-shift, edge lanes via LDS ---
    float oldm = 0.f, oldn = 0.f;
    if (lane == 0)  oldm = s_edge[(wave + 7) & 7][1];
    if (lane == 63) oldn = s_edge[(wave + 1) & 7][0];
    float xm1 = dpp_shift<0x138>(oldm, x[7]);   // wave_shr1: lane i <- lane i-1
    if (it) {
      float xn8 = dpp_shift<0x130>(oldn, x[0]); // wave_shl1: lane i <- lane i+1
      eta[7] = fmaf(10.f, (xn8 - x[7]) - u7prev, eta[7]);
      tau[7] = fmaf(5.f, x[7] - w7prev, tau[7]);
    }
    // --- u, w, r ---
    float u[EPT], w[EPT], r[EPT];
#pragma unroll
    for (int j = 0; j < EPT; ++j) {
      float xprev = (j == 0) ? xm1 : x[j - 1];
      float v = xprev - x[j] + eta[j] * 0.1f;
      u[j] = copysignf(fmaxf(fabsf(v) - 1e-5f, 0.f), v);
      w[j] = fmaxf(fmaf(tau[j], 0.2f, x[j]), 0.f);
      r[j] = bA[j] + 10.f * u[j] - eta[j] + 5.f * w[j] - tau[j];
    }
    // --- zeta partials (from r directly) + DPP wave reduce ---
    float zp[MM];
#pragma unroll
    for (int m = 0; m < MM; ++m) {
      float s = 0.f;
#pragma unroll
      for (int j = 0; j < EPT; ++j) s = fmaf(GH[m][j], r[j], s);
      zp[m] = wave_sum(s);
    }
    if (lane == 63) {
      *(float4*)&s_wq[wave][0] = make_float4(zp[0], zp[1], zp[2], zp[3]);
      *(float4*)&s_wq[wave][4] = make_float4(zp[4], zp[5], zp[6], zp[7]);
      s_wq[wave][8] = zp[8];
    }
    // --- solveM local scans + seed publish ---
    float pl0[EPT];
    solveM_pre(r, pl0, s_sc, t);
    __syncthreads();                            // BARRIER A
    // --- finish solve ---
    float p[EPT];
    solveM_post(pl0, p, s_sc, t);
    // --- z: lanes 0..8 combine one component each, broadcast to SGPRs ---
    float zv = 0.f;
    if (lane < MM) {
#pragma unroll
      for (int wv = 0; wv < 8; ++wv) zv += s_wq[wv][lane];
    }
    float z[MM];
#pragma unroll
    for (int m = 0; m < MM; ++m) z[m] = bcast_lane(zv, m);
    // --- x = p - GH z (in place) ---
#pragma unroll
    for (int j = 0; j < EPT; ++j) {
      float s = p[j];
#pragma unroll
      for (int m = 0; m < MM; ++m) s = fmaf(-GH[m][j], z[m], s);
      x[j] = s;
    }
    if (lane == 0)  s_edge[wave][0] = x[0];
    if (lane == 63) s_edge[wave][1] = x[7];
    // --- duals j=0..6 now; j=7 deferred to next iteration ---
#pragma unroll
    for (int j = 0; j < EPT - 1; ++j) {
      eta[j] = fmaf(10.f, (x[j + 1] - x[j]) - u[j], eta[j]);
      tau[j] = fmaf(5.f, x[j] - w[j], tau[j]);
    }
    u7prev = u[7]; w7prev = w[7];
    __syncthreads();                            // BARRIER B
  }

  // ---- output ----
  float4 o0, o1;
  o0.x = x[0]; o0.y = x[1]; o0.z = x[2]; o0.w = x[3];
  o1.x = x[4]; o1.y = x[5]; o1.z = x[6]; o1.w = x[7];
  *(float4*)(out + base) = o0;
  *(float4*)(out + base + 4) = o1;
}

extern "C" void kernel_launch(void* const* d_in, const int* in_sizes, int n_in,
                              void* d_out, int out_size, void* d_ws, size_t ws_size,
                              hipStream_t stream) {
  const float* target = (const float*)d_in[0];
  const float* A      = (const float*)d_in[1];
  const float* x0     = (const float*)d_in[2];
  admm_kernel<<<1, NT, 0, stream>>>(target, A, x0, (float*)d_out);
}